// Round 3
// baseline (353.051 us; speedup 1.0000x reference)
//
#include <hip/hip_runtime.h>

#define DIM 96
#define NBINS 64
#define BSZ 15
#define PADROWS (DIM + BSZ - 1)   /* 110 */
#define C4N 16                    /* float4 per row = 64/4 */
#define RS4 17                    /* padded row stride in float4 (break bank aliasing) */
#define NTHREADS 256
#define STRIPS (NTHREADS / C4N)   /* 16 */
#define PPS (DIM / STRIPS)        /* 6 positions per strip */

// ---------------------------------------------------------------------------
// K1: per-(z,y) line. Gradients -> soft binning into LDS V[110][64] -> forward
// sliding-window sum (15) along x -> write out[z][y][x][64].
// ---------------------------------------------------------------------------
__global__ __launch_bounds__(NTHREADS) void k_bin_xsum(
    const float* __restrict__ in, float* __restrict__ out)
{
    __shared__ float4 V4[PADROWS * RS4];
    float* Vf = (float*)V4;
    const int tid = threadIdx.x;
    const int y = blockIdx.x;
    const int z = blockIdx.y;

    // zero LDS (scatter phase accumulates, tail rows must be zero)
    for (int i = tid; i < PADROWS * RS4; i += NTHREADS)
        V4[i] = make_float4(0.f, 0.f, 0.f, 0.f);
    __syncthreads();

    if (tid < DIM) {
        const int x = tid;
        const int idx = (z * DIM + y) * DIM + x;
        const float xm = (x > 0)       ? in[idx - 1]         : 0.0f;
        const float xp = (x < DIM - 1) ? in[idx + 1]         : 0.0f;
        const float ym = (y > 0)       ? in[idx - DIM]       : 0.0f;
        const float yp = (y < DIM - 1) ? in[idx + DIM]       : 0.0f;
        const float zm = (z > 0)       ? in[idx - DIM * DIM] : 0.0f;
        const float zp = (z < DIM - 1) ? in[idx + DIM * DIM] : 0.0f;
        const float gx = xp - xm, gy = yp - ym, gz = zp - zm;

        const float EPSF  = 2.220446049250313e-16f;
        const float TWOPI = 6.28318530717958647692f;
        const float PIF   = 3.14159265358979323846f;

        const float r = sqrtf(gx * gx + gy * gy + gz * gz);
        float theta = atanf(gy / (gx + EPSF));
        const float phi = acosf(gz / (r + EPSF));
        if (theta < 0.0f) theta += TWOPI;
        const float t_raw = theta / (TWOPI / 8.0f);
        const float p_raw = phi   / (PIF   / 8.0f);
        const float ft = floorf(t_raw);
        const float fp = floorf(p_raw);
        int lt = (int)ft; if (lt == 8) lt = 0;
        int lp = (int)fp; if (lp == 8) lp = 0;
        const int ht = (lt + 1) & 7;
        const int hp = (lp + 1) & 7;
        const float frac  = t_raw - ft;
        const float w_lo  = fminf(frac, 1.0f - frac);
        const float w_hi  = 1.0f - w_lo;
        const float wp_lo = (frac == 0.0f) ? 1.0f : w_lo;  // faithful: theta frac gates phi split
        const float wp_hi = 1.0f - wp_lo;

        float* vrow = Vf + x * (RS4 * 4);
        vrow[lt * 8 + lp] += r * w_lo * wp_lo;
        vrow[ht * 8 + lp] += r * w_hi * wp_lo;
        vrow[lt * 8 + hp] += r * w_lo * wp_hi;
        vrow[ht * 8 + hp] += r * w_hi * wp_hi;
    }
    __syncthreads();

    // forward sliding-window sum along x, running-window per strip
    const int c4    = tid & (C4N - 1);
    const int strip = tid >> 4;
    int pos = strip * PPS;

    float4 s = make_float4(0.f, 0.f, 0.f, 0.f);
    #pragma unroll
    for (int d = 0; d < BSZ; ++d) {
        const float4 v = V4[(pos + d) * RS4 + c4];
        s.x += v.x; s.y += v.y; s.z += v.z; s.w += v.w;
    }
    float4* out4 = (float4*)out;
    const int base = (z * DIM + y) * DIM * C4N;
    out4[base + pos * C4N + c4] = s;
    #pragma unroll
    for (int j = 1; j < PPS; ++j) {
        const float4 a = V4[pos * RS4 + c4];
        const float4 b = V4[(pos + BSZ) * RS4 + c4];
        s.x += b.x - a.x; s.y += b.y - a.y; s.z += b.z - a.z; s.w += b.w - a.w;
        ++pos;
        out4[base + pos * C4N + c4] = s;
    }
}

// ---------------------------------------------------------------------------
// K2/K3: in-place forward sliding-window sum of 15 along an arbitrary axis.
// One block per line; line element (pos, c4) lives at float4 index
//   base4 + pos*stride4 + c4,  base4 = (blockIdx.y*mulY + blockIdx.x)*16.
// All reads happen before the barrier, all writes after -> in-place safe.
// ---------------------------------------------------------------------------
__global__ __launch_bounds__(NTHREADS) void k_axis_sum(
    float* __restrict__ data, const int mulY, const int stride4)
{
    __shared__ float4 V4[PADROWS * RS4];
    const int tid = threadIdx.x;
    const int base4 = (blockIdx.y * mulY + blockIdx.x) * C4N;
    float4* data4 = (float4*)data;

    for (int i = tid; i < DIM * C4N; i += NTHREADS) {
        const int pos = i >> 4, c4 = i & 15;
        V4[pos * RS4 + c4] = data4[base4 + pos * stride4 + c4];
    }
    for (int i = tid; i < (PADROWS - DIM) * C4N; i += NTHREADS) {
        const int pos = DIM + (i >> 4), c4 = i & 15;
        V4[pos * RS4 + c4] = make_float4(0.f, 0.f, 0.f, 0.f);
    }
    __syncthreads();

    const int c4    = tid & (C4N - 1);
    const int strip = tid >> 4;
    int pos = strip * PPS;

    float4 s = make_float4(0.f, 0.f, 0.f, 0.f);
    #pragma unroll
    for (int d = 0; d < BSZ; ++d) {
        const float4 v = V4[(pos + d) * RS4 + c4];
        s.x += v.x; s.y += v.y; s.z += v.z; s.w += v.w;
    }
    data4[base4 + pos * stride4 + c4] = s;
    #pragma unroll
    for (int j = 1; j < PPS; ++j) {
        const float4 a = V4[pos * RS4 + c4];
        const float4 b = V4[(pos + BSZ) * RS4 + c4];
        s.x += b.x - a.x; s.y += b.y - a.y; s.z += b.z - a.z; s.w += b.w - a.w;
        ++pos;
        data4[base4 + pos * stride4 + c4] = s;
    }
}

extern "C" void kernel_launch(void* const* d_in, const int* in_sizes, int n_in,
                              void* d_out, int out_size, void* d_ws, size_t ws_size,
                              hipStream_t stream) {
    (void)in_sizes; (void)n_in; (void)d_ws; (void)ws_size; (void)out_size;
    const float* x = (const float*)d_in[0];
    float* out = (float*)d_out;

    dim3 grid(DIM, DIM), block(NTHREADS);
    // Pass 1: binning + x-axis window, writes every output element
    k_bin_xsum<<<grid, block, 0, stream>>>(x, out);
    // Pass 2: y-axis window in place. (z,x) line: base=(z*96*96 + x)*16, stride=96*16
    k_axis_sum<<<grid, block, 0, stream>>>(out, DIM * DIM, DIM * C4N);
    // Pass 3: z-axis window in place. (y,x) line: base=(y*96 + x)*16, stride=96*96*16
    k_axis_sum<<<grid, block, 0, stream>>>(out, DIM, DIM * DIM * C4N);
}